// Round 2
// baseline (431.687 us; speedup 1.0000x reference)
//
#include <hip/hip_runtime.h>
#include <hip/hip_bf16.h>
#include <stdint.h>

// ---------------------------------------------------------------- geometry
#define E_DIM 512
#define GNB   35        // basis functions per input feature (G + K_DEG)
#define KSP   17920     // 512*35 spline K
#define KAUG  18432     // spline + base (512)
#define MTOK  2048      // B*L
#define BKW   128       // K window (cols per LDS tile)
#define NWIN  144       // KAUG/BKW
#define WINB  140       // first base-branch window (17920/128, exact)
#define BM    128
#define BN    128
#define RB    256       // row bytes in LDS tiles (BKW * 2)

typedef __attribute__((ext_vector_type(8))) short  short8;   // 8 bf16 (4 VGPR) MFMA A/B frag
typedef __attribute__((ext_vector_type(4))) short  short4v;
typedef __attribute__((ext_vector_type(4))) float  floatx4;  // MFMA C/D frag + indexable float4

__device__ __forceinline__ short f2bf(float f) {
  __hip_bfloat16 h = __float2bfloat16(f);
  return *reinterpret_cast<short*>(&h);
}
__device__ __forceinline__ float silu_f(float x) { return x / (1.0f + __expf(-x)); }

__device__ __forceinline__ void gload_lds16(const void* g, void* l) {
  typedef const __attribute__((address_space(1))) void* gp_t;
  typedef __attribute__((address_space(3))) void* lp_t;
  __builtin_amdgcn_global_load_lds((gp_t)g, (lp_t)l, 16, 0, 0);
}

// T2 swizzle: permute 16B chunks within a 128B half-row by XOR of row&7.
// Applied identically on write-side addressing and read-side addressing.
__device__ __forceinline__ int swz(int row, int byte_off) {
  return row * RB + (byte_off ^ ((row & 7) << 4));
}

// ---------------------------------------------------------------------------
// wconv (FULL path only): [KAUG x 512] f32 (w_sp rows k=e*35+g, w_base rows
// k=17920+e) -> bf16 waugT[3][512][KAUG] (o-major, k contiguous, LINEAR).
// ---------------------------------------------------------------------------
__global__ __launch_bounds__(256) void wconv_kernel(
    const float* __restrict__ wq_sp, const float* __restrict__ wq_base,
    const float* __restrict__ wk_sp, const float* __restrict__ wk_base,
    const float* __restrict__ wv_sp, const float* __restrict__ wv_base,
    __hip_bfloat16* __restrict__ waugT)
{
  __shared__ float tile[64][65];  // +1 pad: conflict-free transposed reads
  const int tz = blockIdx.z;
  const float* wsp = tz == 0 ? wq_sp : (tz == 1 ? wk_sp : wv_sp);
  const float* wb  = tz == 0 ? wq_base : (tz == 1 ? wk_base : wv_base);
  const int k0 = blockIdx.x * 64;
  const int o0 = blockIdx.y * 64;
  const int t  = threadIdx.x;
#pragma unroll
  for (int it = 0; it < 16; ++it) {
    int idx = it * 256 + t;
    int r = idx >> 6, c = idx & 63;
    int k = k0 + r;
    float val = (k < KSP) ? wsp[(size_t)k * E_DIM + (o0 + c)]
                          : wb[(size_t)(k - KSP) * E_DIM + (o0 + c)];
    tile[r][c] = val;
  }
  __syncthreads();
  __hip_bfloat16* dst = waugT + (size_t)tz * E_DIM * KAUG;
#pragma unroll
  for (int it = 0; it < 16; ++it) {
    int idx = it * 256 + t;
    int r = idx >> 6, c = idx & 63;   // r: o row, c: k col (coalesced writes)
    dst[(size_t)(o0 + r) * KAUG + (k0 + c)] = __float2bfloat16(tile[c][r]);
  }
}

// ---------------------------------------------------------------------------
// Fused KAN GEMM: C[tz] = [basis(X) | silu(X)] @ W_aug.  A built in LDS.
// MODE 0: B staged via global_load_lds from bf16 waugT (source pre-swizzled).
// MODE 1: B staged from original f32 weights, reg transpose, swizzled writes.
// grid (16 mtiles, 4 ntiles, 3 tensors * 4 k-quarters); block 256 (4 waves).
// ---------------------------------------------------------------------------
template<int MODE>
__global__ __launch_bounds__(256) void kan_gemm(
    const float* __restrict__ q, const float* __restrict__ k_in,
    const float* __restrict__ v, const __hip_bfloat16* __restrict__ waugT,
    const float* __restrict__ wq_sp, const float* __restrict__ wq_base,
    const float* __restrict__ wk_sp, const float* __restrict__ wk_base,
    const float* __restrict__ wv_sp, const float* __restrict__ wv_base,
    float* __restrict__ C)
{
  __shared__ int4 sAq[BM * 16];   // 32 KB, swizzled [BM][256B]
  __shared__ int4 sBq[BN * 16];   // 32 KB, swizzled [BN][256B]
  char* pA = (char*)sAq;
  char* pB = (char*)sBq;

  const int z  = blockIdx.z;        // 0..11
  const int tz = z >> 2;
  const int ks = z & 3;             // split-K quarter
  const float* X = tz == 0 ? q : (tz == 1 ? k_in : v);
  const float* Wsp = tz == 0 ? wq_sp : (tz == 1 ? wk_sp : wv_sp);
  const float* Wb  = tz == 0 ? wq_base : (tz == 1 ? wk_base : wv_base);
  const char* WTb = (const char*)(waugT + (size_t)tz * E_DIM * KAUG);
  float* Cout = C + (size_t)tz * MTOK * E_DIM;

  const int m0 = blockIdx.x * BM;
  const int n0 = blockIdx.y * BN;
  const int t = threadIdx.x;
  const int lane = t & 63, wid = t >> 6;
  const int wm = wid >> 1, wn = wid & 1;    // 2x2 waves of 64x64
  const int fr = lane & 15, kg = lane >> 4;

  floatx4 acc[4][4];
  const floatx4 zf = {0.f, 0.f, 0.f, 0.f};
#pragma unroll
  for (int i = 0; i < 4; ++i)
#pragma unroll
    for (int j = 0; j < 4; ++j) acc[i][j] = zf;

  const int w_lo = ks * (NWIN / 4), w_hi = w_lo + (NWIN / 4);
  for (int win = w_lo; win < w_hi; ++win) {
    const int k0 = win * BKW;
    const bool spline = (win < WINB);
    __syncthreads();   // previous window's frag reads complete

    // ------------------------------------------------ stage B tile
    if (MODE == 0) {
      // linear LDS dest (wave-uniform base + lane*16), swizzle via source addr
      const int rB = t >> 4;
      const int cb = (t & 15) * 16;           // byte within row
#pragma unroll
      for (int p = 0; p < 8; ++p) {
        int row = p * 16 + rB;
        size_t goff = ((size_t)(n0 + row) * KAUG + k0) * 2
                    + (size_t)(cb ^ ((row & 7) << 4));
        gload_lds16(WTb + goff, pB + row * RB + cb);
      }
    } else {
      // f32 weights, lane-mapped so swizzled LDS writes are ~2-way
      const float* Wrow = spline ? Wsp : Wb;
      const int koff0 = spline ? k0 : k0 - KSP;
      const int g  = t & 31;        // n fine index
      const int rg = t >> 5;        // k row-group (0..7)
#pragma unroll
      for (int p = 0; p < 4; ++p) {
        const int r0 = (p * 8 + rg) * 4;      // k-local base (0..124, step 4)
        float rv[4][4];                        // [j: k][j2: n]
#pragma unroll
        for (int j = 0; j < 4; ++j) {
          const float* src = &Wrow[(size_t)(koff0 + r0 + j) * E_DIM + n0 + g];
#pragma unroll
          for (int j2 = 0; j2 < 4; ++j2) rv[j][j2] = src[32 * j2];
        }
#pragma unroll
        for (int j2 = 0; j2 < 4; ++j2) {
          const int nloc = g + 32 * j2;
          short4v sv;
          sv.x = f2bf(rv[0][j2]); sv.y = f2bf(rv[1][j2]);
          sv.z = f2bf(rv[2][j2]); sv.w = f2bf(rv[3][j2]);
          *(short4v*)&pB[swz(nloc, 2 * r0)] = sv;
        }
      }
    }

    // ------------------------------------------------ build A tile
    if (spline) {
      // zero then scatter 4 cardinal cubic B-spline weights per (m, e)
      const int4 z4 = make_int4(0, 0, 0, 0);
#pragma unroll
      for (int p = 0; p < 8; ++p) sAq[p * 256 + t] = z4;
      __syncthreads();
      const int elo = k0 / GNB;
      int ehi = (k0 + BKW - 1) / GNB; if (ehi > 511) ehi = 511;
      const int ne = ehi - elo + 1;            // 4 or 5
      const int npairs = BM * ne;
      for (int p = t; p < npairs; p += 256) {
        int m, ei;
        if (ne == 4) { m = p >> 2; ei = p & 3; }
        else         { m = (p * 52429) >> 18; ei = p - m * 5; }
        const int e = elo + ei;
        float x = X[(size_t)(m0 + m) * E_DIM + e];
        x = fminf(fmaxf(x, -3.0f), 3.0f - 1e-4f);
        float u = (x + 3.0f) * (16.0f / 3.0f);
        int ii = (int)u; ii = ii > 31 ? 31 : ii;
        float tt = u - (float)ii;
        float omt = 1.0f - tt;
        float t2 = tt * tt, t3 = t2 * tt;
        float b0 = omt * omt * omt * (1.0f / 6.0f);
        float b1 = (3.0f * t3 - 6.0f * t2 + 4.0f) * (1.0f / 6.0f);
        float b2 = (-3.0f * t3 + 3.0f * t2 + 3.0f * tt + 1.0f) * (1.0f / 6.0f);
        float b3 = t3 * (1.0f / 6.0f);
        const int c = e * GNB + ii - k0;
        if (c >= 0     && c < BKW)     *(short*)&pA[swz(m, 2 * c)]       = f2bf(b0);
        if (c + 1 >= 0 && c + 1 < BKW) *(short*)&pA[swz(m, 2 * (c + 1))] = f2bf(b1);
        if (c + 2 >= 0 && c + 2 < BKW) *(short*)&pA[swz(m, 2 * (c + 2))] = f2bf(b2);
        if (c + 3 >= 0 && c + 3 < BKW) *(short*)&pA[swz(m, 2 * (c + 3))] = f2bf(b3);
      }
    } else {
      // base window: A = silu(x) dense (128 e-columns of X)
      const int e0 = k0 - KSP;
#pragma unroll
      for (int p = 0; p < 16; ++p) {
        int idx = p * 256 + t;
        int m = idx >> 5, c4 = idx & 31;
        floatx4 xv = *(const floatx4*)&X[(size_t)(m0 + m) * E_DIM + e0 + c4 * 4];
        short4v pk;
        pk.x = f2bf(silu_f(xv.x)); pk.y = f2bf(silu_f(xv.y));
        pk.z = f2bf(silu_f(xv.z)); pk.w = f2bf(silu_f(xv.w));
        *(short4v*)&pA[swz(m, 8 * c4)] = pk;
      }
    }
    __syncthreads();   // A ready; barrier drains vmcnt -> B ready

    // ------------------------------------------------ MFMA 4 k-chunks
#pragma unroll
    for (int kc = 0; kc < 4; ++kc) {
      const int kb = kc * 64 + kg * 16;        // byte offset in row
      short8 af[4], bfv[4];
#pragma unroll
      for (int fm = 0; fm < 4; ++fm) {
        const int row = wm * 64 + fm * 16 + fr;
        af[fm] = *(const short8*)&pA[swz(row, kb)];
      }
#pragma unroll
      for (int fn = 0; fn < 4; ++fn) {
        const int col = wn * 64 + fn * 16 + fr;
        bfv[fn] = *(const short8*)&pB[swz(col, kb)];
      }
#pragma unroll
      for (int fm = 0; fm < 4; ++fm)
#pragma unroll
        for (int fn = 0; fn < 4; ++fn)
          acc[fm][fn] = __builtin_amdgcn_mfma_f32_16x16x32_bf16(
              af[fm], bfv[fn], acc[fm][fn], 0, 0, 0);
    }
  }

  // ------------------------------------------------ split-K epilogue
  const int rowb = kg * 4;
#pragma unroll
  for (int fm = 0; fm < 4; ++fm)
#pragma unroll
    for (int fn = 0; fn < 4; ++fn)
#pragma unroll
      for (int r = 0; r < 4; ++r)
        atomicAdd(&Cout[(size_t)(m0 + wm * 64 + fm * 16 + rowb + r) * E_DIM
                        + (n0 + wn * 64 + fn * 16 + fr)],
                  acc[fm][fn][r]);
}

// ---------------------------------------------------------------------------
// KtV[b,h,d,e] = sum_s K[b,h,s,d] * V[b,h,s,e]   (f32, s-chunked + atomics)
// ---------------------------------------------------------------------------
__global__ __launch_bounds__(256) void ktv_kernel(const float* __restrict__ C,
                                                  float* __restrict__ KtV)
{
  __shared__ float Ks[64][64];
  __shared__ float Vs[64][64];
  const int sc = blockIdx.x, bh = blockIdx.y;
  const int b = bh >> 3, h = bh & 7;
  const int t = threadIdx.x;
  const size_t base = ((size_t)(b * 1024 + sc * 64)) * E_DIM + h * 64;
  const float* Kp = C + (size_t)MTOK * E_DIM + base;
  const float* Vp = C + (size_t)2 * MTOK * E_DIM + base;
#pragma unroll
  for (int p = 0; p < 16; ++p) {
    int idx = p * 256 + t;
    int r = idx >> 6, c = idx & 63;
    Ks[r][c] = Kp[(size_t)r * E_DIM + c];
    Vs[r][c] = Vp[(size_t)r * E_DIM + c];
  }
  __syncthreads();
  const int d0 = (t & 15) * 4, e0 = (t >> 4) * 4;
  float acc[4][4] = {};
  for (int s = 0; s < 64; ++s) {
    float4 kv = *(const float4*)&Ks[s][d0];
    float4 vv = *(const float4*)&Vs[s][e0];
    float ka[4] = {kv.x, kv.y, kv.z, kv.w};
    float va[4] = {vv.x, vv.y, vv.z, vv.w};
#pragma unroll
    for (int i = 0; i < 4; ++i)
#pragma unroll
      for (int j = 0; j < 4; ++j) acc[i][j] = __fmaf_rn(ka[i], va[j], acc[i][j]);
  }
  float* dst = KtV + (size_t)bh * 4096;
#pragma unroll
  for (int i = 0; i < 4; ++i)
#pragma unroll
    for (int j = 0; j < 4; ++j)
      atomicAdd(&dst[(d0 + i) * 64 + (e0 + j)], acc[i][j]);
}

// ---------------------------------------------------------------------------
// out[b,l,h*64+e] = sum_d Q[b,l,h,d] * KtV[b,h,d,e]
// ---------------------------------------------------------------------------
__global__ __launch_bounds__(256) void qktv_kernel(const float* __restrict__ C,
                                                   const float* __restrict__ KtV,
                                                   float* __restrict__ out)
{
  __shared__ float Qs[128][64];
  __shared__ float Ms[64][64];
  const int lt = blockIdx.x, bh = blockIdx.y;
  const int b = bh >> 3, h = bh & 7;
  const int t = threadIdx.x;
  const float* Qp = C + ((size_t)(b * 1024 + lt * 128)) * E_DIM + h * 64;
#pragma unroll
  for (int p = 0; p < 32; ++p) {
    int idx = p * 256 + t;
    Qs[idx >> 6][idx & 63] = Qp[(size_t)(idx >> 6) * E_DIM + (idx & 63)];
  }
#pragma unroll
  for (int p = 0; p < 16; ++p) {
    int idx = p * 256 + t;
    Ms[idx >> 6][idx & 63] = KtV[(size_t)bh * 4096 + idx];
  }
  __syncthreads();
  const int e0 = (t & 15) * 4;
  const int l0 = (t >> 4) * 8;
  float acc[8][4] = {};
  for (int d = 0; d < 64; ++d) {
    float4 mv = *(const float4*)&Ms[d][e0];
    float ma[4] = {mv.x, mv.y, mv.z, mv.w};
#pragma unroll
    for (int i = 0; i < 8; ++i) {
      float qv = Qs[l0 + i][d];
#pragma unroll
      for (int j = 0; j < 4; ++j) acc[i][j] = __fmaf_rn(qv, ma[j], acc[i][j]);
    }
  }
  float* op = out + ((size_t)(b * 1024 + lt * 128)) * E_DIM + h * 64;
#pragma unroll
  for (int i = 0; i < 8; ++i)
#pragma unroll
    for (int j = 0; j < 4; ++j)
      op[(size_t)(l0 + i) * E_DIM + (e0 + j)] = acc[i][j];
}

// ---------------------------------------------------------------------------
extern "C" void kernel_launch(void* const* d_in, const int* in_sizes, int n_in,
                              void* d_out, int out_size, void* d_ws, size_t ws_size,
                              hipStream_t stream) {
  const float* q   = (const float*)d_in[0];
  const float* k   = (const float*)d_in[1];
  const float* v   = (const float*)d_in[2];
  const float* wqb = (const float*)d_in[3];
  const float* wqs = (const float*)d_in[4];
  const float* wkb = (const float*)d_in[5];
  const float* wks = (const float*)d_in[6];
  const float* wvb = (const float*)d_in[7];
  const float* wvs = (const float*)d_in[8];

  char* ws = (char*)d_ws;
  const size_t WAUG_BYTES = (size_t)3 * E_DIM * KAUG * sizeof(__hip_bfloat16); // 56.6 MB
  const size_t C_BYTES    = (size_t)3 * MTOK * E_DIM * sizeof(float);          // 12.6 MB
  const size_t KTV_BYTES  = (size_t)16 * 64 * 64 * sizeof(float);              // 256 KB
  const bool full = ws_size >= WAUG_BYTES + C_BYTES + KTV_BYTES;               // ws_size is
                                                                               // call-invariant
  float* C;
  float* KtV;
  __hip_bfloat16* waugT = (__hip_bfloat16*)ws;
  if (full) { C = (float*)(ws + WAUG_BYTES); KtV = (float*)(ws + WAUG_BYTES + C_BYTES); }
  else      { C = (float*)ws;                KtV = (float*)(ws + C_BYTES); }

  hipMemsetAsync(C, 0, C_BYTES, stream);
  hipMemsetAsync(KtV, 0, KTV_BYTES, stream);

  if (full) {
    wconv_kernel<<<dim3(KAUG / 64, E_DIM / 64, 3), 256, 0, stream>>>(
        wqs, wqb, wks, wkb, wvs, wvb, waugT);
    kan_gemm<0><<<dim3(MTOK / BM, E_DIM / BN, 12), 256, 0, stream>>>(
        q, k, v, waugT, wqs, wqb, wks, wkb, wvs, wvb, C);
  } else {
    kan_gemm<1><<<dim3(MTOK / BM, E_DIM / BN, 12), 256, 0, stream>>>(
        q, k, v, waugT, wqs, wqb, wks, wkb, wvs, wvb, C);
  }
  ktv_kernel<<<dim3(16, 16), 256, 0, stream>>>(C, KtV);
  qktv_kernel<<<dim3(8, 16), 256, 0, stream>>>(C, KtV, (float*)d_out);
}